// Round 17
// baseline (157.199 us; speedup 1.0000x reference)
//
#include <hip/hip_runtime.h>
#include <cstdint>
#include <cstddef>

#define VOCAB 50000
#define EMBED 256
#define BATCH 16384
#define NSAMP 4096

typedef float f32x4 __attribute__((ext_vector_type(4)));
typedef int   i32x4 __attribute__((ext_vector_type(4)));
typedef int   i32x8 __attribute__((ext_vector_type(8)));

// ---------- helpers ----------

__device__ __forceinline__ f32x4 vsplat(float a) {
    f32x4 r = {a, a, a, a};
    return r;
}

// Pure-HW log(expected_count): no libm calls (validated r6-r8, absmax 0.0).
__device__ __forceinline__ float log_expected_count(int id) {
    float u = 1.0f / ((float)id + 1.0f);
    float a = __logf(1.0f + u);
    float p = a * 0.09242324f;   // 1/log(50001)
    float ser = p * (1.0f + p * (0.5f + p * (0.33333333f + p * (0.25f + p * 0.2f))));
    float q = -(float)NSAMP * ser;
    return __logf(1.0f - __expf(q));
}

// softplus(x) = max(x,0) + log1p(e^{-|x|}); deg-5 minimax (|err|<=1e-5)
__device__ __forceinline__ float softplus_f(float x) {
    float v = __expf(-fabsf(x));
    float p = fmaf(v, 0.03215845f, -0.13606275f);
    p = fmaf(v, p, 0.28947478f);
    p = fmaf(v, p, -0.49190896f);
    p = fmaf(v, p, 0.99949556f);
    return fmaxf(x, 0.0f) + v * p;
}

// Packed-f32 softplus over 4 elements, 4-wide acc chain.
__device__ __forceinline__ void softplus4_acc(f32x4 x, f32x4& vsum) {
    f32x4 ax = __builtin_elementwise_abs(x);
    f32x4 v;
    v.x = __expf(-ax.x);
    v.y = __expf(-ax.y);
    v.z = __expf(-ax.z);
    v.w = __expf(-ax.w);
    f32x4 p = __builtin_elementwise_fma(v, vsplat(0.03215845f), vsplat(-0.13606275f));
    p = __builtin_elementwise_fma(v, p, vsplat(0.28947478f));
    p = __builtin_elementwise_fma(v, p, vsplat(-0.49190896f));
    p = __builtin_elementwise_fma(v, p, vsplat(0.99949556f));
    vsum += __builtin_elementwise_max(x, vsplat(0.0f));
    vsum = __builtin_elementwise_fma(v, p, vsum);
}

// pack 4 floats -> 4 fp8 e4m3 bytes (HW cvt, OCP on gfx950)
__device__ __forceinline__ int pk4_fp8(float a, float b, float c, float d) {
    int v = __builtin_amdgcn_cvt_pk_fp8_f32(a, b, 0, false);
    v = __builtin_amdgcn_cvt_pk_fp8_f32(c, d, v, true);
    return v;
}

// EF (A matrix) layout — 32B-chunk fragment order:
//   offset(r,k) = (r>>4)*4096 + (k>>5)*512 + (r&15)*32 + (k&31)
// BF (B matrix) layout — 16B-plane split (LDS bank-even reads):
//   offset(r,k) = (r>>4)*4096 + (k>>5)*512 + ((k>>4)&1)*256 + (r&15)*16 + (k&15)

// ---------- kernels ----------

// blocks [0,1024): true logits + E -> fp8 fragments (1 wave = 4 rows)
// blocks [1024,1088): gather W[sids] * 16 -> fp8 fragments + badj
__global__ __launch_bounds__(256) void k_prep(
        const float* __restrict__ E, const int* __restrict__ tgt,
        const int* __restrict__ sids, const float* __restrict__ W,
        const float* __restrict__ bias,
        unsigned char* __restrict__ EF, unsigned char* __restrict__ BF,
        float* __restrict__ badj, double* __restrict__ pTrue)
{
    const int blk = blockIdx.x, tid = threadIdx.x;
    const int wave = tid >> 6, lane = tid & 63;

    if (blk < 1024) {
        float tsum = 0.0f;
        #pragma unroll
        for (int i = 0; i < 4; ++i) {
            int b = (blk * 4 + wave) + 4096 * i;
            int label = tgt[b];
            float4 e  = ((const float4*)(E + (size_t)b * EMBED))[lane];
            float4 wv = ((const float4*)(W + (size_t)label * EMBED))[lane];
            int pk = pk4_fp8(e.x, e.y, e.z, e.w);
            *(int*)(EF + ((b >> 4) * 4096 + (lane >> 3) * 512
                          + (b & 15) * 32 + (lane & 7) * 4)) = pk;
            float d = e.x * wv.x + e.y * wv.y + e.z * wv.z + e.w * wv.w;
            #pragma unroll
            for (int off = 32; off > 0; off >>= 1) d += __shfl_down(d, off, 64);
            if (lane == 0) {
                float tl = d + bias[label] - log_expected_count(label);
                tsum += softplus_f(-tl);
            }
        }
        __shared__ float ts[4];
        if (lane == 0) ts[wave] = tsum;
        __syncthreads();
        if (tid == 0) pTrue[blk] = (double)((ts[0] + ts[1]) + (ts[2] + ts[3]));
    } else {
        #pragma unroll
        for (int i = 0; i < 4; ++i) {
            int task = (blk - 1024) * 256 + tid + 16384 * i;
            int s = task >> 4, p = task & 15;   // p = 16B chunk, k = p*16
            int sid = sids[s];
            const float4* wr = (const float4*)(W + (size_t)sid * EMBED + p * 16);
            float4 w0 = wr[0], w1 = wr[1], w2 = wr[2], w3 = wr[3];
            int4 o;
            o.x = pk4_fp8(w0.x * 16.0f, w0.y * 16.0f, w0.z * 16.0f, w0.w * 16.0f);
            o.y = pk4_fp8(w1.x * 16.0f, w1.y * 16.0f, w1.z * 16.0f, w1.w * 16.0f);
            o.z = pk4_fp8(w2.x * 16.0f, w2.y * 16.0f, w2.z * 16.0f, w2.w * 16.0f);
            o.w = pk4_fp8(w3.x * 16.0f, w3.y * 16.0f, w3.z * 16.0f, w3.w * 16.0f);
            // plane-split store: q = p>>1, h = p&1
            *(int4*)(BF + ((s >> 4) * 4096 + (p >> 1) * 512 + (p & 1) * 256
                           + (s & 15) * 16)) = o;
            if (p == 0) badj[s] = bias[sid] - log_expected_count(sid);
        }
    }
}

// GEMM: MX-fp8, A in registers, B staged in LDS once per block.
// r15: OCCUPANCY-QUANTUM fix. r14's counters proved memory irrelevant
// (L3-warm runs: 64KB HBM traffic, same 45us) and both pipes <35% busy.
// Per m69, waves/CU halve at VGPR={64,128,256}; every prior config sat at
// the SAME 16-waves/CU quantum (VGPR in (64,128] OR 64KB LDS -> 2 blocks).
// This config breaks into the 32-waves quantum: grid 2048 (256x128 tile),
// 32KB LDS panel, hard 64-VGPR cap via __launch_bounds__(512,8).
// Live set fits: af[2][2]=32 + bf=8 (per-s sequential) + acc[2]=8 +
// vsum 4 + misc ~10 = ~62. 4 blocks/CU x 8 waves = 32 waves/CU -> 2x the
// latency hiding ever achieved. r14's fused atomic reduce reverted (tail).
__global__ __launch_bounds__(512, 8) void k_gemm(
        const unsigned char* __restrict__ EF,
        const unsigned char* __restrict__ BF,
        const float* __restrict__ badj,
        double* __restrict__ pGemm)
{
    const int tid  = threadIdx.x;
    const int wave = tid >> 6;            // 0..7
    const int lane = tid & 63;
    const int rg   = blockIdx.x >> 5;     // 256-row group (0..63)
    const int cg2  = blockIdx.x & 31;     // 128-col group (0..31)
    const int ag0  = rg * 16 + wave * 2;  // A 16-row group base (2 groups/wave)
    const int r16  = lane & 15;

    __shared__ unsigned char Blds[32768];
    __shared__ float wsum[8];

    // A fragments: 2 k-steps x 2 row-groups = 4 x 32B per lane (32 VGPR).
    i32x8 af[2][2];
    #pragma unroll
    for (int s = 0; s < 2; ++s)
        #pragma unroll
        for (int mi = 0; mi < 2; ++mi)
            af[s][mi] = *(const i32x8*)(EF + (size_t)(ag0 + mi) * 4096
                                        + s * 2048 + lane * 32);

    // Cooperative stage of the 32KB B panel (linear byte copy; the 8
    // fragment groups cg2*8..cg2*8+7 are contiguous in BF).
    {
        const unsigned char* Bsrc = BF + (size_t)cg2 * 32768;
        #pragma unroll
        for (int it = 0; it < 4; ++it) {
            int woff = it * 8192 + wave * 1024;   // wave-uniform LDS base
            int goff = woff + lane * 16;
            __builtin_amdgcn_global_load_lds(
                (const __attribute__((address_space(1))) void*)(Bsrc + goff),
                (__attribute__((address_space(3))) void*)(Blds + woff),
                16, 0, 0);
        }
    }

    asm volatile("s_waitcnt vmcnt(0)");
    __syncthreads();

    // Pin af in registers (r1 lesson: allocator re-sinks global loads).
    #pragma unroll
    for (int s = 0; s < 2; ++s)
        #pragma unroll
        for (int mi = 0; mi < 2; ++mi)
            asm volatile("" : "+v"(af[s][mi]));

    f32x4 vsum = {};
    const int lbase = (lane >> 4) * 512 + r16 * 16;  // per-lane base in 4KB group
    const float* bb = badj + cg2 * 128 + r16;

    #pragma unroll 1
    for (int cgi = 0; cgi < 8; ++cgi) {       // 16-col group within block's 128
        float ba = bb[cgi * 16];

        f32x4 acc[2] = {};
        #pragma unroll
        for (int s = 0; s < 2; ++s) {         // per-s sequential: bf live = 8
            const unsigned char* bp = Blds + cgi * 4096 + s * 2048 + lbase;
            i32x4 lo = *(const i32x4*)bp;          // k 0..15 of lane's 32
            i32x4 hi = *(const i32x4*)(bp + 256);  // k 16..31
            i32x8 bf;
            bf[0] = lo[0]; bf[1] = lo[1]; bf[2] = lo[2]; bf[3] = lo[3];
            bf[4] = hi[0]; bf[5] = hi[1]; bf[6] = hi[2]; bf[7] = hi[3];
            #pragma unroll
            for (int mi = 0; mi < 2; ++mi)
                acc[mi] = __builtin_amdgcn_mfma_scale_f32_16x16x128_f8f6f4(
                    af[s][mi], bf, acc[mi],
                    0, 0,                 // cbsz=fp8, blgp=fp8
                    0, 0x7F7F7F7F,        // scale A = 2^0
                    0, 0x7B7B7B7B);       // scale B = 2^-4 (undo W*16)
        }

        #pragma unroll
        for (int mi = 0; mi < 2; ++mi)
            softplus4_acc(acc[mi] + vsplat(ba), vsum);
    }

    float lsum = (vsum.x + vsum.y) + (vsum.z + vsum.w);
    #pragma unroll
    for (int off = 32; off > 0; off >>= 1) lsum += __shfl_down(lsum, off, 64);
    if (lane == 0) wsum[wave] = lsum;
    __syncthreads();
    if (tid == 0)
        pGemm[blockIdx.x] = (double)((((wsum[0] + wsum[1]) + (wsum[2] + wsum[3]))
                                    + ((wsum[4] + wsum[5]) + (wsum[6] + wsum[7]))));
}

__global__ __launch_bounds__(256) void k_final(
        const double* __restrict__ pTrue, const double* __restrict__ pGemm,
        float* __restrict__ out)
{
    const int tid = threadIdx.x, wave = tid >> 6, lane = tid & 63;
    double s = 0.0;
    for (int i = tid; i < 1024; i += 256) s += pTrue[i];
    for (int i = tid; i < 2048; i += 256) s += pGemm[i];
    #pragma unroll
    for (int off = 32; off > 0; off >>= 1) s += __shfl_down(s, off, 64);
    __shared__ double wsum[4];
    if (lane == 0) wsum[wave] = s;
    __syncthreads();
    if (tid == 0)
        out[0] = (float)(((wsum[0] + wsum[1]) + (wsum[2] + wsum[3]))
                         * (1.0 / (double)BATCH));
}

// ---------- launch ----------

extern "C" void kernel_launch(void* const* d_in, const int* in_sizes, int n_in,
                              void* d_out, int out_size, void* d_ws, size_t ws_size,
                              hipStream_t stream) {
    const float* emb  = (const float*)d_in[0];
    const int*   tgt  = (const int*)d_in[1];
    const int*   sids = (const int*)d_in[2];
    const float* W    = (const float*)d_in[3];
    const float* bias = (const float*)d_in[4];
    float* out = (float*)d_out;

    char* ws = (char*)d_ws;
    double*        pTrue = (double*)ws;                        // 1024 doubles
    double*        pGemm = (double*)(ws + 8192);               // 2048 doubles
    float*         badj  = (float*)(ws + 40960);               // 16 KB
    unsigned char* BF    = (unsigned char*)(ws + 57344);       // 1 MB
    unsigned char* EF    = (unsigned char*)(ws + 57344 + 1048576); // 4 MB

    hipLaunchKernelGGL(k_prep, dim3(1088), dim3(256), 0, stream,
                       emb, tgt, sids, W, bias, EF, BF, badj, pTrue);
    hipLaunchKernelGGL(k_gemm, dim3(2048), dim3(512), 0, stream,
                       EF, BF, badj, pGemm);
    hipLaunchKernelGGL(k_final, dim3(1), dim3(256), 0, stream,
                       pTrue, pGemm, out);
}

// Round 19
// 135.040 us; speedup vs baseline: 1.1641x; 1.1641x over previous
//
#include <hip/hip_runtime.h>
#include <cstdint>
#include <cstddef>

#define VOCAB 50000
#define EMBED 256
#define BATCH 16384
#define NSAMP 4096

typedef float f32x4 __attribute__((ext_vector_type(4)));
typedef int   i32x4 __attribute__((ext_vector_type(4)));
typedef int   i32x8 __attribute__((ext_vector_type(8)));

// ---------- helpers ----------

__device__ __forceinline__ f32x4 vsplat(float a) {
    f32x4 r = {a, a, a, a};
    return r;
}

// Pure-HW log(expected_count): no libm calls (validated r6-r8, absmax 0.0).
__device__ __forceinline__ float log_expected_count(int id) {
    float u = 1.0f / ((float)id + 1.0f);
    float a = __logf(1.0f + u);
    float p = a * 0.09242324f;   // 1/log(50001)
    float ser = p * (1.0f + p * (0.5f + p * (0.33333333f + p * (0.25f + p * 0.2f))));
    float q = -(float)NSAMP * ser;
    return __logf(1.0f - __expf(q));
}

// softplus(x) = max(x,0) + log1p(e^{-|x|}); deg-5 minimax. Used only in
// k_prep's true-logit path (16K elements) where logits are unbounded-safe.
__device__ __forceinline__ float softplus_f(float x) {
    float v = __expf(-fabsf(x));
    float p = fmaf(v, 0.03215845f, -0.13606275f);
    p = fmaf(v, p, 0.28947478f);
    p = fmaf(v, p, -0.49190896f);
    p = fmaf(v, p, 0.99949556f);
    return fmaxf(x, 0.0f) + v * p;
}

// r18 epilogue: EXACT softplus via ln(1+e^x), accumulated in log2 domain.
// Valid because sampled logits are bounded (~[-6,12]; e^x overflows only
// at x>88). Per f32x4: 2 pk (x) + 4 mul + 4 v_exp + 2 pk (1+e) + 4 v_log
// + 2 pk acc ~= 16 VALU issues vs softplus4_acc's ~26 (abs/max/deg-4
// poly eliminated). Final x ln2 applied once per wave.
__device__ __forceinline__ void softplus4_log2(f32x4 x, f32x4& lg) {
    f32x4 e;
    e.x = __expf(x.x);
    e.y = __expf(x.y);
    e.z = __expf(x.z);
    e.w = __expf(x.w);
    f32x4 u = e + vsplat(1.0f);
    lg.x += __log2f(u.x);
    lg.y += __log2f(u.y);
    lg.z += __log2f(u.z);
    lg.w += __log2f(u.w);
}

// pack 4 floats -> 4 fp8 e4m3 bytes (HW cvt, OCP on gfx950)
__device__ __forceinline__ int pk4_fp8(float a, float b, float c, float d) {
    int v = __builtin_amdgcn_cvt_pk_fp8_f32(a, b, 0, false);
    v = __builtin_amdgcn_cvt_pk_fp8_f32(c, d, v, true);
    return v;
}

// EF (A matrix) layout — 32B-chunk fragment order:
//   offset(r,k) = (r>>4)*4096 + (k>>5)*512 + (r&15)*32 + (k&31)
// BF (B matrix) layout — 16B-plane split (LDS bank-even reads):
//   offset(r,k) = (r>>4)*4096 + (k>>5)*512 + ((k>>4)&1)*256 + (r&15)*16 + (k&15)

// ---------- kernels ----------

// blocks [0,1024): true logits + E -> fp8 fragments (1 wave = 4 rows)
// blocks [1024,1088): gather W[sids] * 16 -> fp8 fragments + badj
__global__ __launch_bounds__(256) void k_prep(
        const float* __restrict__ E, const int* __restrict__ tgt,
        const int* __restrict__ sids, const float* __restrict__ W,
        const float* __restrict__ bias,
        unsigned char* __restrict__ EF, unsigned char* __restrict__ BF,
        float* __restrict__ badj, double* __restrict__ pTrue)
{
    const int blk = blockIdx.x, tid = threadIdx.x;
    const int wave = tid >> 6, lane = tid & 63;

    if (blk < 1024) {
        float tsum = 0.0f;
        #pragma unroll
        for (int i = 0; i < 4; ++i) {
            int b = (blk * 4 + wave) + 4096 * i;
            int label = tgt[b];
            float4 e  = ((const float4*)(E + (size_t)b * EMBED))[lane];
            float4 wv = ((const float4*)(W + (size_t)label * EMBED))[lane];
            int pk = pk4_fp8(e.x, e.y, e.z, e.w);
            *(int*)(EF + ((b >> 4) * 4096 + (lane >> 3) * 512
                          + (b & 15) * 32 + (lane & 7) * 4)) = pk;
            float d = e.x * wv.x + e.y * wv.y + e.z * wv.z + e.w * wv.w;
            #pragma unroll
            for (int off = 32; off > 0; off >>= 1) d += __shfl_down(d, off, 64);
            if (lane == 0) {
                float tl = d + bias[label] - log_expected_count(label);
                tsum += softplus_f(-tl);
            }
        }
        __shared__ float ts[4];
        if (lane == 0) ts[wave] = tsum;
        __syncthreads();
        if (tid == 0) pTrue[blk] = (double)((ts[0] + ts[1]) + (ts[2] + ts[3]));
    } else {
        #pragma unroll
        for (int i = 0; i < 4; ++i) {
            int task = (blk - 1024) * 256 + tid + 16384 * i;
            int s = task >> 4, p = task & 15;   // p = 16B chunk, k = p*16
            int sid = sids[s];
            const float4* wr = (const float4*)(W + (size_t)sid * EMBED + p * 16);
            float4 w0 = wr[0], w1 = wr[1], w2 = wr[2], w3 = wr[3];
            int4 o;
            o.x = pk4_fp8(w0.x * 16.0f, w0.y * 16.0f, w0.z * 16.0f, w0.w * 16.0f);
            o.y = pk4_fp8(w1.x * 16.0f, w1.y * 16.0f, w1.z * 16.0f, w1.w * 16.0f);
            o.z = pk4_fp8(w2.x * 16.0f, w2.y * 16.0f, w2.z * 16.0f, w2.w * 16.0f);
            o.w = pk4_fp8(w3.x * 16.0f, w3.y * 16.0f, w3.z * 16.0f, w3.w * 16.0f);
            // plane-split store: q = p>>1, h = p&1
            *(int4*)(BF + ((s >> 4) * 4096 + (p >> 1) * 512 + (p & 1) * 256
                           + (s & 15) * 16)) = o;
            if (p == 0) badj[s] = bias[sid] - log_expected_count(sid);
        }
    }
}

// GEMM: MX-fp8, A in registers, B staged in LDS once per block.
// Geometry = r11 (best measured: 129.0us total, k_gemm ~34us): 8 waves,
// (512,4) = 128-VGPR budget, 64KB LDS, 2 blocks/CU. r17's (512,8) probe
// proved occupancy is NOT the limiter (Occ 63%, dur worse, spills), and
// r14's L3-warm dispatches proved memory traffic is irrelevant. The
// remaining large pipe is the epilogue VALU (~26 issues/f32x4, ~13us/CU,
// serialized after each acc tile) -> r18 swaps in the 16-issue exact
// log/exp softplus (softplus4_log2 above). Everything else untouched.
__global__ __launch_bounds__(512, 4) void k_gemm(
        const unsigned char* __restrict__ EF,
        const unsigned char* __restrict__ BF,
        const float* __restrict__ badj,
        double* __restrict__ pGemm)
{
    const int tid  = threadIdx.x;
    const int wave = tid >> 6;            // 0..7
    const int lane = tid & 63;
    const int rg   = blockIdx.x >> 4;     // 256-row group (0..63)
    const int cg   = blockIdx.x & 15;     // 256-col group (0..15)
    const int ag0  = rg * 16 + wave * 2;  // A 16-row group base (2 groups/wave)
    const int r16  = lane & 15;

    __shared__ unsigned char Blds[65536];
    __shared__ float wsum[8];

    // A fragments: 2 k-steps x 2 row-groups = 4 x 32B per lane.
    i32x8 af[2][2];
    #pragma unroll
    for (int s = 0; s < 2; ++s)
        #pragma unroll
        for (int mi = 0; mi < 2; ++mi)
            af[s][mi] = *(const i32x8*)(EF + (size_t)(ag0 + mi) * 4096
                                        + s * 2048 + lane * 32);

    // Cooperative stage of the 64KB B panel (linear byte copy).
    {
        const unsigned char* Bsrc = BF + (size_t)cg * 65536;
        #pragma unroll
        for (int it = 0; it < 8; ++it) {
            int woff = it * 8192 + wave * 1024;   // wave-uniform LDS base
            int goff = woff + lane * 16;
            __builtin_amdgcn_global_load_lds(
                (const __attribute__((address_space(1))) void*)(Bsrc + goff),
                (__attribute__((address_space(3))) void*)(Blds + woff),
                16, 0, 0);
        }
    }

    asm volatile("s_waitcnt vmcnt(0)");
    __syncthreads();

    // Pin af in registers (r1 lesson: allocator re-sinks global loads).
    #pragma unroll
    for (int s = 0; s < 2; ++s)
        #pragma unroll
        for (int mi = 0; mi < 2; ++mi)
            asm volatile("" : "+v"(af[s][mi]));

    f32x4 lg = {};                       // log2-domain accumulator
    const int lbase = (lane >> 4) * 512 + r16 * 16;  // per-lane base in 4KB group

    #pragma unroll 1
    for (int j = 0; j < 4; ++j) {
        i32x8 bf[2][4];
        #pragma unroll
        for (int s = 0; s < 2; ++s)
            #pragma unroll
            for (int ni = 0; ni < 4; ++ni) {
                const unsigned char* bp = Blds + (j * 4 + ni) * 4096
                                          + s * 2048 + lbase;
                i32x4 lo = *(const i32x4*)bp;          // k 0..15 of lane's 32
                i32x4 hi = *(const i32x4*)(bp + 256);  // k 16..31
                bf[s][ni][0] = lo[0]; bf[s][ni][1] = lo[1];
                bf[s][ni][2] = lo[2]; bf[s][ni][3] = lo[3];
                bf[s][ni][4] = hi[0]; bf[s][ni][5] = hi[1];
                bf[s][ni][6] = hi[2]; bf[s][ni][7] = hi[3];
            }

        float ba[4];
        #pragma unroll
        for (int ni = 0; ni < 4; ++ni)
            ba[ni] = badj[cg * 256 + j * 64 + ni * 16 + r16];

        #pragma unroll
        for (int mi = 0; mi < 2; ++mi) {
            f32x4 acc[4] = {};
            #pragma unroll
            for (int s = 0; s < 2; ++s)
                #pragma unroll
                for (int ni = 0; ni < 4; ++ni)
                    acc[ni] = __builtin_amdgcn_mfma_scale_f32_16x16x128_f8f6f4(
                        af[s][mi], bf[s][ni], acc[ni],
                        0, 0,                 // cbsz=fp8, blgp=fp8
                        0, 0x7F7F7F7F,        // scale A = 2^0
                        0, 0x7B7B7B7B);       // scale B = 2^-4 (undo W*16)
            #pragma unroll
            for (int ni = 0; ni < 4; ++ni)
                softplus4_log2(acc[ni] + vsplat(ba[ni]), lg);
        }
    }

    // lg holds sum of log2(1+e^x); convert to natural-log domain once.
    float lsum = ((lg.x + lg.y) + (lg.z + lg.w)) * 0.69314718f;
    #pragma unroll
    for (int off = 32; off > 0; off >>= 1) lsum += __shfl_down(lsum, off, 64);
    if (lane == 0) wsum[wave] = lsum;
    __syncthreads();
    if (tid == 0)
        pGemm[blockIdx.x] = (double)((((wsum[0] + wsum[1]) + (wsum[2] + wsum[3]))
                                    + ((wsum[4] + wsum[5]) + (wsum[6] + wsum[7]))));
}

__global__ __launch_bounds__(256) void k_final(
        const double* __restrict__ pTrue, const double* __restrict__ pGemm,
        float* __restrict__ out)
{
    const int tid = threadIdx.x, wave = tid >> 6, lane = tid & 63;
    double s = 0.0;
    for (int i = tid; i < 1024; i += 256) s += pTrue[i];
    for (int i = tid; i < 1024; i += 256) s += pGemm[i];
    #pragma unroll
    for (int off = 32; off > 0; off >>= 1) s += __shfl_down(s, off, 64);
    __shared__ double wsum[4];
    if (lane == 0) wsum[wave] = s;
    __syncthreads();
    if (tid == 0)
        out[0] = (float)(((wsum[0] + wsum[1]) + (wsum[2] + wsum[3]))
                         * (1.0 / (double)BATCH));
}

// ---------- launch ----------

extern "C" void kernel_launch(void* const* d_in, const int* in_sizes, int n_in,
                              void* d_out, int out_size, void* d_ws, size_t ws_size,
                              hipStream_t stream) {
    const float* emb  = (const float*)d_in[0];
    const int*   tgt  = (const int*)d_in[1];
    const int*   sids = (const int*)d_in[2];
    const float* W    = (const float*)d_in[3];
    const float* bias = (const float*)d_in[4];
    float* out = (float*)d_out;

    char* ws = (char*)d_ws;
    double*        pTrue = (double*)ws;                        // 1024 doubles
    double*        pGemm = (double*)(ws + 8192);               // 1024 doubles
    float*         badj  = (float*)(ws + 40960);               // 16 KB
    unsigned char* BF    = (unsigned char*)(ws + 57344);       // 1 MB
    unsigned char* EF    = (unsigned char*)(ws + 57344 + 1048576); // 4 MB

    hipLaunchKernelGGL(k_prep, dim3(1088), dim3(256), 0, stream,
                       emb, tgt, sids, W, bias, EF, BF, badj, pTrue);
    hipLaunchKernelGGL(k_gemm, dim3(1024), dim3(512), 0, stream,
                       EF, BF, badj, pGemm);
    hipLaunchKernelGGL(k_final, dim3(1), dim3(256), 0, stream,
                       pTrue, pGemm, out);
}

// Round 20
// 131.080 us; speedup vs baseline: 1.1993x; 1.0302x over previous
//
#include <hip/hip_runtime.h>
#include <cstdint>
#include <cstddef>

#define VOCAB 50000
#define EMBED 256
#define BATCH 16384
#define NSAMP 4096

typedef float f32x4 __attribute__((ext_vector_type(4)));
typedef int   i32x4 __attribute__((ext_vector_type(4)));
typedef int   i32x8 __attribute__((ext_vector_type(8)));

// ---------- helpers ----------

__device__ __forceinline__ f32x4 vsplat(float a) {
    f32x4 r = {a, a, a, a};
    return r;
}

// Pure-HW log(expected_count): no libm calls (validated r6-r8, absmax 0.0).
__device__ __forceinline__ float log_expected_count(int id) {
    float u = 1.0f / ((float)id + 1.0f);
    float a = __logf(1.0f + u);
    float p = a * 0.09242324f;   // 1/log(50001)
    float ser = p * (1.0f + p * (0.5f + p * (0.33333333f + p * (0.25f + p * 0.2f))));
    float q = -(float)NSAMP * ser;
    return __logf(1.0f - __expf(q));
}

// softplus(x) = max(x,0) + log1p(e^{-|x|}); deg-5 minimax (|err|<=1e-5).
// r19 lesson: this is the CYCLE-optimal form — 4 trans + 22 cheap ~= 62cy
// per f32x4. The "fewer issues" log2 variant (8 trans) measured +6us WORSE
// (transcendentals are 1/4-rate). Do not swap this out again.
__device__ __forceinline__ float softplus_f(float x) {
    float v = __expf(-fabsf(x));
    float p = fmaf(v, 0.03215845f, -0.13606275f);
    p = fmaf(v, p, 0.28947478f);
    p = fmaf(v, p, -0.49190896f);
    p = fmaf(v, p, 0.99949556f);
    return fmaxf(x, 0.0f) + v * p;
}

// Packed-f32 softplus over 4 elements, 4-wide acc chain.
__device__ __forceinline__ void softplus4_acc(f32x4 x, f32x4& vsum) {
    f32x4 ax = __builtin_elementwise_abs(x);
    f32x4 v;
    v.x = __expf(-ax.x);
    v.y = __expf(-ax.y);
    v.z = __expf(-ax.z);
    v.w = __expf(-ax.w);
    f32x4 p = __builtin_elementwise_fma(v, vsplat(0.03215845f), vsplat(-0.13606275f));
    p = __builtin_elementwise_fma(v, p, vsplat(0.28947478f));
    p = __builtin_elementwise_fma(v, p, vsplat(-0.49190896f));
    p = __builtin_elementwise_fma(v, p, vsplat(0.99949556f));
    vsum += __builtin_elementwise_max(x, vsplat(0.0f));
    vsum = __builtin_elementwise_fma(v, p, vsum);
}

// pack 4 floats -> 4 fp8 e4m3 bytes (HW cvt, OCP on gfx950)
__device__ __forceinline__ int pk4_fp8(float a, float b, float c, float d) {
    int v = __builtin_amdgcn_cvt_pk_fp8_f32(a, b, 0, false);
    v = __builtin_amdgcn_cvt_pk_fp8_f32(c, d, v, true);
    return v;
}

// EF (A matrix) layout — 32B-chunk fragment order:
//   offset(r,k) = (r>>4)*4096 + (k>>5)*512 + (r&15)*32 + (k&31)
// BF (B matrix) layout — 16B-plane split (LDS bank-even reads):
//   offset(r,k) = (r>>4)*4096 + (k>>5)*512 + ((k>>4)&1)*256 + (r&15)*16 + (k&15)

// ---------- kernels ----------

// blocks [0,1024): true logits + E -> fp8 fragments (1 wave = 4 rows)
// blocks [1024,1088): gather W[sids] * 16 -> fp8 fragments + badj
__global__ __launch_bounds__(256) void k_prep(
        const float* __restrict__ E, const int* __restrict__ tgt,
        const int* __restrict__ sids, const float* __restrict__ W,
        const float* __restrict__ bias,
        unsigned char* __restrict__ EF, unsigned char* __restrict__ BF,
        float* __restrict__ badj, double* __restrict__ pTrue)
{
    const int blk = blockIdx.x, tid = threadIdx.x;
    const int wave = tid >> 6, lane = tid & 63;

    if (blk < 1024) {
        float tsum = 0.0f;
        #pragma unroll
        for (int i = 0; i < 4; ++i) {
            int b = (blk * 4 + wave) + 4096 * i;
            int label = tgt[b];
            float4 e  = ((const float4*)(E + (size_t)b * EMBED))[lane];
            float4 wv = ((const float4*)(W + (size_t)label * EMBED))[lane];
            int pk = pk4_fp8(e.x, e.y, e.z, e.w);
            *(int*)(EF + ((b >> 4) * 4096 + (lane >> 3) * 512
                          + (b & 15) * 32 + (lane & 7) * 4)) = pk;
            float d = e.x * wv.x + e.y * wv.y + e.z * wv.z + e.w * wv.w;
            #pragma unroll
            for (int off = 32; off > 0; off >>= 1) d += __shfl_down(d, off, 64);
            if (lane == 0) {
                float tl = d + bias[label] - log_expected_count(label);
                tsum += softplus_f(-tl);
            }
        }
        __shared__ float ts[4];
        if (lane == 0) ts[wave] = tsum;
        __syncthreads();
        if (tid == 0) pTrue[blk] = (double)((ts[0] + ts[1]) + (ts[2] + ts[3]));
    } else {
        #pragma unroll
        for (int i = 0; i < 4; ++i) {
            int task = (blk - 1024) * 256 + tid + 16384 * i;
            int s = task >> 4, p = task & 15;   // p = 16B chunk, k = p*16
            int sid = sids[s];
            const float4* wr = (const float4*)(W + (size_t)sid * EMBED + p * 16);
            float4 w0 = wr[0], w1 = wr[1], w2 = wr[2], w3 = wr[3];
            int4 o;
            o.x = pk4_fp8(w0.x * 16.0f, w0.y * 16.0f, w0.z * 16.0f, w0.w * 16.0f);
            o.y = pk4_fp8(w1.x * 16.0f, w1.y * 16.0f, w1.z * 16.0f, w1.w * 16.0f);
            o.z = pk4_fp8(w2.x * 16.0f, w2.y * 16.0f, w2.z * 16.0f, w2.w * 16.0f);
            o.w = pk4_fp8(w3.x * 16.0f, w3.y * 16.0f, w3.z * 16.0f, w3.w * 16.0f);
            // plane-split store: q = p>>1, h = p&1
            *(int4*)(BF + ((s >> 4) * 4096 + (p >> 1) * 512 + (p & 1) * 256
                           + (s & 15) * 16)) = o;
            if (p == 0) badj[s] = bias[sid] - log_expected_count(sid);
        }
    }
}

// GEMM: MX-fp8, A in registers, B staged in LDS — r20: CHUNKED staging with
// counted vmcnt (T3/T4). r11 base (129.0us best) had the anti-pattern:
// vmcnt(0) + __syncthreads before ALL compute — every wave dead until the
// whole 64KB panel lands. Now: all 8 staging loads issued in chunk order
// (chunk j = 16KB = j-iteration's exact working set, 2 loads/thread); per j,
// wait vmcnt(6-2j) (only chunk j retired, younger chunks stay in flight) +
// RAW s_barrier (avoids __syncthreads' compiler-forced full drain). Compute
// of j overlaps the landing of chunks j+1..3. vmcnt literals are correct
// under any af/staging interleave (counts only assume staging issue order).
__global__ __launch_bounds__(512, 4) void k_gemm(
        const unsigned char* __restrict__ EF,
        const unsigned char* __restrict__ BF,
        const float* __restrict__ badj,
        double* __restrict__ pGemm)
{
    const int tid  = threadIdx.x;
    const int wave = tid >> 6;            // 0..7
    const int lane = tid & 63;
    const int rg   = blockIdx.x >> 4;     // 256-row group (0..63)
    const int cg   = blockIdx.x & 15;     // 256-col group (0..15)
    const int ag0  = rg * 16 + wave * 2;  // A 16-row group base (2 groups/wave)
    const int r16  = lane & 15;

    __shared__ unsigned char Blds[65536];
    __shared__ float wsum[8];

    // A fragments first: 2 k-steps x 2 row-groups = 4 x 32B per lane.
    i32x8 af[2][2];
    #pragma unroll
    for (int s = 0; s < 2; ++s)
        #pragma unroll
        for (int mi = 0; mi < 2; ++mi)
            af[s][mi] = *(const i32x8*)(EF + (size_t)(ag0 + mi) * 4096
                                        + s * 2048 + lane * 32);

    // Issue ALL staging loads in chunk order (it 0..7; chunk j = its 2j,2j+1).
    {
        const unsigned char* Bsrc = BF + (size_t)cg * 65536;
        #pragma unroll
        for (int it = 0; it < 8; ++it) {
            int woff = it * 8192 + wave * 1024;   // wave-uniform LDS base
            int goff = woff + lane * 16;
            __builtin_amdgcn_global_load_lds(
                (const __attribute__((address_space(1))) void*)(Bsrc + goff),
                (__attribute__((address_space(3))) void*)(Blds + woff),
                16, 0, 0);
        }
    }

    // Pin af (forces the af waits here; r1 lesson: prevents re-sinking).
    #pragma unroll
    for (int s = 0; s < 2; ++s)
        #pragma unroll
        for (int mi = 0; mi < 2; ++mi)
            asm volatile("" : "+v"(af[s][mi]));

    f32x4 vsum = {};
    const int lbase = (lane >> 4) * 512 + r16 * 16;  // per-lane base in 4KB group

#define COMPUTE_J(J, VM) do {                                               \
        asm volatile("s_waitcnt vmcnt(" #VM ")" ::: "memory");              \
        __builtin_amdgcn_s_barrier();                                       \
        __builtin_amdgcn_sched_barrier(0);                                  \
        i32x8 bf[2][4];                                                     \
        _Pragma("unroll")                                                   \
        for (int s_ = 0; s_ < 2; ++s_)                                      \
            _Pragma("unroll")                                               \
            for (int ni_ = 0; ni_ < 4; ++ni_) {                             \
                const unsigned char* bp = Blds + ((J) * 4 + ni_) * 4096     \
                                          + s_ * 2048 + lbase;              \
                i32x4 lo = *(const i32x4*)bp;                               \
                i32x4 hi = *(const i32x4*)(bp + 256);                       \
                bf[s_][ni_][0] = lo[0]; bf[s_][ni_][1] = lo[1];             \
                bf[s_][ni_][2] = lo[2]; bf[s_][ni_][3] = lo[3];             \
                bf[s_][ni_][4] = hi[0]; bf[s_][ni_][5] = hi[1];             \
                bf[s_][ni_][6] = hi[2]; bf[s_][ni_][7] = hi[3];             \
            }                                                               \
        float ba[4];                                                        \
        _Pragma("unroll")                                                   \
        for (int ni_ = 0; ni_ < 4; ++ni_)                                   \
            ba[ni_] = badj[cg * 256 + (J) * 64 + ni_ * 16 + r16];           \
        _Pragma("unroll")                                                   \
        for (int mi_ = 0; mi_ < 2; ++mi_) {                                 \
            f32x4 acc[4] = {};                                              \
            _Pragma("unroll")                                               \
            for (int s_ = 0; s_ < 2; ++s_)                                  \
                _Pragma("unroll")                                           \
                for (int ni_ = 0; ni_ < 4; ++ni_)                           \
                    acc[ni_] = __builtin_amdgcn_mfma_scale_f32_16x16x128_f8f6f4( \
                        af[s_][mi_], bf[s_][ni_], acc[ni_],                 \
                        0, 0,                 /* cbsz=fp8, blgp=fp8 */      \
                        0, 0x7F7F7F7F,        /* scale A = 2^0 */           \
                        0, 0x7B7B7B7B);       /* scale B = 2^-4 */          \
            _Pragma("unroll")                                               \
            for (int ni_ = 0; ni_ < 4; ++ni_)                               \
                softplus4_acc(acc[ni_] + vsplat(ba[ni_]), vsum);            \
        }                                                                   \
    } while (0)

    COMPUTE_J(0, 6);
    COMPUTE_J(1, 4);
    COMPUTE_J(2, 2);
    COMPUTE_J(3, 0);

#undef COMPUTE_J

    float lsum = (vsum.x + vsum.y) + (vsum.z + vsum.w);
    #pragma unroll
    for (int off = 32; off > 0; off >>= 1) lsum += __shfl_down(lsum, off, 64);
    if (lane == 0) wsum[wave] = lsum;
    __syncthreads();
    if (tid == 0)
        pGemm[blockIdx.x] = (double)((((wsum[0] + wsum[1]) + (wsum[2] + wsum[3]))
                                    + ((wsum[4] + wsum[5]) + (wsum[6] + wsum[7]))));
}

__global__ __launch_bounds__(256) void k_final(
        const double* __restrict__ pTrue, const double* __restrict__ pGemm,
        float* __restrict__ out)
{
    const int tid = threadIdx.x, wave = tid >> 6, lane = tid & 63;
    double s = 0.0;
    for (int i = tid; i < 1024; i += 256) s += pTrue[i];
    for (int i = tid; i < 1024; i += 256) s += pGemm[i];
    #pragma unroll
    for (int off = 32; off > 0; off >>= 1) s += __shfl_down(s, off, 64);
    __shared__ double wsum[4];
    if (lane == 0) wsum[wave] = s;
    __syncthreads();
    if (tid == 0)
        out[0] = (float)(((wsum[0] + wsum[1]) + (wsum[2] + wsum[3]))
                         * (1.0 / (double)BATCH));
}

// ---------- launch ----------

extern "C" void kernel_launch(void* const* d_in, const int* in_sizes, int n_in,
                              void* d_out, int out_size, void* d_ws, size_t ws_size,
                              hipStream_t stream) {
    const float* emb  = (const float*)d_in[0];
    const int*   tgt  = (const int*)d_in[1];
    const int*   sids = (const int*)d_in[2];
    const float* W    = (const float*)d_in[3];
    const float* bias = (const float*)d_in[4];
    float* out = (float*)d_out;

    char* ws = (char*)d_ws;
    double*        pTrue = (double*)ws;                        // 1024 doubles
    double*        pGemm = (double*)(ws + 8192);               // 1024 doubles
    float*         badj  = (float*)(ws + 40960);               // 16 KB
    unsigned char* BF    = (unsigned char*)(ws + 57344);       // 1 MB
    unsigned char* EF    = (unsigned char*)(ws + 57344 + 1048576); // 4 MB

    hipLaunchKernelGGL(k_prep, dim3(1088), dim3(256), 0, stream,
                       emb, tgt, sids, W, bias, EF, BF, badj, pTrue);
    hipLaunchKernelGGL(k_gemm, dim3(1024), dim3(512), 0, stream,
                       EF, BF, badj, pGemm);
    hipLaunchKernelGGL(k_final, dim3(1), dim3(256), 0, stream,
                       pTrue, pGemm, out);
}